// Round 5
// baseline (737.413 us; speedup 1.0000x reference)
//
#include <hip/hip_runtime.h>
#include <hip/hip_bf16.h>
#include <cstdint>

#define N_NODES 50000
#define N_EDGES 800000

// ---------------------------------------------------------------------------
// feat = X @ W  and el/er = per-head attention dots.
// 256 threads = 4 waves. Block tile: 64 rows x DOUT cols.
// Lane l owns row (row0+l); wave w owns cols [w*DOUT/4, +DOUT/4).
// W[k][c] is wave-uniform -> SGPR (s_load) double-buffered; X staged in LDS
// padded [64][KP+1] so per-k ds_read_b32 is bank-conflict-free.
template<int DIN, int DOUT, int F>
__global__ __launch_bounds__(256) void gemm_attn(
    const float* __restrict__ X, const float* __restrict__ W,
    const float* __restrict__ al, const float* __restrict__ ar,
    float* __restrict__ feat, float* __restrict__ el, float* __restrict__ er, int N)
{
    constexpr int KP  = (DIN > 128) ? 128 : DIN;  // k-phase size
    constexpr int NPH = DIN / KP;                 // phases
    constexpr int CPW = DOUT / 4;                 // cols per wave (= per lane)
    constexpr int H   = DOUT / F;
    constexpr int STR = KP + 1;                   // padded LDS row stride

    __shared__ float xs[64][STR];                 // 33 KB for KP=128
    __shared__ float pred[2][4][64];              // cross-wave dot reduce (L2)

    const int tid  = threadIdx.x;
    const int wid  = tid >> 6;
    const int lane = tid & 63;
    const int row0 = blockIdx.x * 64;
    const int row  = row0 + lane;
    const int col0 = wid * CPW;

    float acc[CPW];
#pragma unroll
    for (int c = 0; c < CPW; ++c) acc[c] = 0.f;

    for (int ph = 0; ph < NPH; ++ph) {
        __syncthreads();
        // stage 64 rows x KP floats (coalesced float4 reads, b32 LDS writes)
        for (int slot = tid; slot < 64 * (KP / 4); slot += 256) {
            int r = slot / (KP / 4), q = slot % (KP / 4);
            int rr = min(row0 + r, N - 1);
            const float4 v = *reinterpret_cast<const float4*>(
                &X[(size_t)rr * DIN + ph * KP + 4 * q]);
            xs[r][4 * q + 0] = v.x;
            xs[r][4 * q + 1] = v.y;
            xs[r][4 * q + 2] = v.z;
            xs[r][4 * q + 3] = v.w;
        }
        __syncthreads();

        const float* Wk = W + (size_t)ph * KP * DOUT + col0;

        float wA[CPW], wB[CPW];
#pragma unroll
        for (int c = 0; c < CPW; ++c) wA[c] = Wk[c];        // k = 0
        float xv0 = xs[lane][0];

        for (int k = 0; k < KP; k += 2) {
            // prefetch k+1 (SGPR buffer B + next x)
#pragma unroll
            for (int c = 0; c < CPW; ++c) wB[c] = Wk[(size_t)(k + 1) * DOUT + c];
            float xv1 = xs[lane][k + 1];
#pragma unroll
            for (int c = 0; c < CPW; ++c) acc[c] = fmaf(xv0, wA[c], acc[c]);
            // prefetch k+2 into buffer A
            if (k + 2 < KP) {
#pragma unroll
                for (int c = 0; c < CPW; ++c) wA[c] = Wk[(size_t)(k + 2) * DOUT + c];
                xv0 = xs[lane][k + 2];
            }
#pragma unroll
            for (int c = 0; c < CPW; ++c) acc[c] = fmaf(xv1, wB[c], acc[c]);
        }
    }

    // ---- attention dots (al/ar flat index == global column index) ----
    if constexpr (F <= CPW) {
        constexpr int HPW = CPW / F;              // heads per wave (2 for L0/L1)
#pragma unroll
        for (int hh = 0; hh < HPW; ++hh) {
            float pl = 0.f, pr = 0.f;
#pragma unroll
            for (int f = 0; f < F; ++f) {
                int c = hh * F + f;
                pl = fmaf(acc[c], al[col0 + c], pl);
                pr = fmaf(acc[c], ar[col0 + c], pr);
            }
            if (row < N) {
                int h = col0 / F + hh;
                el[(size_t)row * H + h] = pl;
                er[(size_t)row * H + h] = pr;
            }
        }
    } else {
        // F spans waves (L2: F=64, CPW=16): partial dot + LDS reduce
        float pl = 0.f, pr = 0.f;
#pragma unroll
        for (int c = 0; c < CPW; ++c) {
            pl = fmaf(acc[c], al[col0 + c], pl);
            pr = fmaf(acc[c], ar[col0 + c], pr);
        }
        pred[0][wid][lane] = pl;
        pred[1][wid][lane] = pr;
        __syncthreads();
        if (wid == 0 && row < N) {
            float l = pred[0][0][lane] + pred[0][1][lane] + pred[0][2][lane] + pred[0][3][lane];
            float r = pred[1][0][lane] + pred[1][1][lane] + pred[1][2][lane] + pred[1][3][lane];
            el[row] = l;
            er[row] = r;
        }
    }

    // ---- feat store: each lane's CPW cols are contiguous ----
    if (row < N) {
#pragma unroll
        for (int q = 0; q < CPW / 4; ++q) {
            float4 v = make_float4(acc[4 * q], acc[4 * q + 1], acc[4 * q + 2], acc[4 * q + 3]);
            *reinterpret_cast<float4*>(&feat[(size_t)row * DOUT + col0 + 4 * q]) = v;
        }
    }
}

// ---------------------------------------------------------------------------
// CSR build (dst-sorted), shared by all 3 layers
__global__ void zero_ints(int* __restrict__ a, int n)
{
    int i = blockIdx.x * blockDim.x + threadIdx.x;
    if (i < n) a[i] = 0;
}

__global__ void hist_deg(const int* __restrict__ dst, int* __restrict__ deg)
{
    int e = blockIdx.x * blockDim.x + threadIdx.x;
    if (e < N_EDGES) atomicAdd(&deg[dst[e]], 1);
}

// single block, 1024 threads: exclusive scan of deg[0..n) -> offs[0..n]
__global__ __launch_bounds__(1024) void scan_offsets(
    const int* __restrict__ deg, int* __restrict__ offs, int n)
{
    __shared__ int wtot[16], wincl[16];
    __shared__ int carry_s;
    const int tid = threadIdx.x;
    const int lane = tid & 63, wid = tid >> 6;
    if (tid == 0) carry_s = 0;
    __syncthreads();
    for (int base = 0; base < n; base += 1024) {
        int i = base + tid;
        int v = (i < n) ? deg[i] : 0;
        int x = v;
#pragma unroll
        for (int off = 1; off < 64; off <<= 1) {
            int t = __shfl_up(x, off);
            if (lane >= off) x += t;
        }
        if (lane == 63) wtot[wid] = x;
        __syncthreads();
        if (tid < 16) {
            int wx = wtot[tid];
#pragma unroll
            for (int off = 1; off < 16; off <<= 1) {
                int t = __shfl_up(wx, off);
                if (tid >= off) wx += t;
            }
            wincl[tid] = wx;
        }
        __syncthreads();
        int waveExcl = (wid == 0) ? 0 : wincl[wid - 1];
        if (i < n) offs[i] = carry_s + waveExcl + (x - v);
        int total = wincl[15];
        __syncthreads();
        if (tid == 0) carry_s += total;
        __syncthreads();
    }
    if (threadIdx.x == 0) offs[n] = carry_s;
}

__global__ void build_csr(const int* __restrict__ src, const int* __restrict__ dst,
                          const int* __restrict__ offs, int* __restrict__ cursor,
                          int* __restrict__ csr_src)
{
    int e = blockIdx.x * blockDim.x + threadIdx.x;
    if (e >= N_EDGES) return;
    int d = dst[e];
    int p = offs[d] + atomicAdd(&cursor[d], 1);
    csr_src[p] = src[e];
}

// ---------------------------------------------------------------------------
// Fused flash-style softmax + aggregation per dst node. One wave per node.
template<int H, int F, bool ACT>
__global__ __launch_bounds__(256) void node_flash_agg(
    const int* __restrict__ offs, const int* __restrict__ csr_src,
    const float* __restrict__ el, const float* __restrict__ er,
    const float* __restrict__ feat, const float* __restrict__ bias,
    float* __restrict__ out, int N)
{
    constexpr int D = H * F;
    constexpr int CPT = D / 64;     // components per lane (2 or 1)
    constexpr int EPC = 64 / H;     // edges per chunk (8 or 64)
    constexpr int SB = 8;           // feat-load batch depth

    const int wid = threadIdx.x >> 6;
    const int lane = threadIdx.x & 63;
    const int n = blockIdx.x * 4 + wid;
    if (n >= N) return;

    const int beg = offs[n];
    const int deg = offs[n + 1] - beg;

    const int h = lane % H;
    const int esub = lane / H;
    const float erd = er[(size_t)n * H + h];

    float m_run = -1e30f, s_run = 0.f;
    float acc[CPT];
#pragma unroll
    for (int c = 0; c < CPT; ++c) acc[c] = 0.f;

    for (int base = 0; base < deg; base += EPC) {
        int ei = base + esub;
        int s_mine = csr_src[beg + min(ei, deg - 1)];   // clamped for padding
        float v = el[(size_t)s_mine * H + h] + erd;
        v = (v > 0.f) ? v : 0.2f * v;                   // leaky_relu 0.2
        float logit = (ei < deg) ? v : -1e30f;

        float cmax = logit;
#pragma unroll
        for (int off = H; off < 64; off <<= 1)
            cmax = fmaxf(cmax, __shfl_xor(cmax, off));
        float nm = fmaxf(m_run, cmax);
        float scale = __expf(m_run - nm);               // 0 on first chunk
        float ex = __expf(logit - nm);                  // 0 for padded lanes
        float csum = ex;
#pragma unroll
        for (int off = H; off < 64; off <<= 1)
            csum += __shfl_xor(csum, off);
        s_run = s_run * scale + csum;
        m_run = nm;

#pragma unroll
        for (int c = 0; c < CPT; ++c)
            acc[c] *= __shfl(scale, (lane + c * 64) / F);

        int active = min(EPC, deg - base);
        for (int g = 0; g < active; g += SB) {
            float fv[SB][CPT];
#pragma unroll
            for (int ii = 0; ii < SB; ++ii) {
                int sl = __shfl(s_mine, (g + ii) * H);  // edge g+ii src row
#pragma unroll
                for (int c = 0; c < CPT; ++c)
                    fv[ii][c] = feat[(size_t)sl * D + lane + c * 64];
            }
#pragma unroll
            for (int ii = 0; ii < SB; ++ii)
#pragma unroll
                for (int c = 0; c < CPT; ++c) {
                    float exb = __shfl(ex, (g + ii) * H + (lane + c * 64) / F);
                    acc[c] = fmaf(fv[ii][c], exb, acc[c]);
                }
        }
    }

    const float inv = (s_run > 0.f) ? 1.f / s_run : 0.f;
#pragma unroll
    for (int c = 0; c < CPT; ++c) {
        int comp = lane + c * 64;
        float v = acc[c] * __shfl(inv, comp / F) + bias[comp];
        if (ACT) v = (v > 0.f) ? v : expm1f(v);         // ELU alpha=1
        out[(size_t)n * D + comp] = v;
    }
}

// ---------------------------------------------------------------------------
extern "C" void kernel_launch(void* const* d_in, const int* in_sizes, int n_in,
                              void* d_out, int out_size, void* d_ws, size_t ws_size,
                              hipStream_t stream)
{
    const float* x   = (const float*)d_in[0];
    const int*   src = (const int*)d_in[1];
    const int*   dst = (const int*)d_in[2];
    const float* W0  = (const float*)d_in[3];
    const float* al0 = (const float*)d_in[4];
    const float* ar0 = (const float*)d_in[5];
    const float* b0  = (const float*)d_in[6];
    const float* W1  = (const float*)d_in[7];
    const float* al1 = (const float*)d_in[8];
    const float* ar1 = (const float*)d_in[9];
    const float* b1  = (const float*)d_in[10];
    const float* W2  = (const float*)d_in[11];
    const float* al2 = (const float*)d_in[12];
    const float* ar2 = (const float*)d_in[13];
    const float* b2  = (const float*)d_in[14];
    float* out = (float*)d_out;

    const int N = N_NODES, E = N_EDGES;

    float* ws   = (float*)d_ws;
    float* feat = ws;                         // N*128
    float* hbuf = feat + (size_t)N * 128;     // N*128
    float* elb  = hbuf + (size_t)N * 128;     // N*8
    float* erb  = elb + (size_t)N * 8;        // N*8
    int* ibase   = (int*)(erb + (size_t)N * 8);
    int* deg     = ibase;                     // N
    int* cursor  = deg + N;                   // N
    int* offs    = cursor + N;                // N+1
    int* csr_src = offs + N + 1;              // E

    const int TB = 256;
    const int gb_rows64 = (N + 63) / 64;
    const int gb_edges  = (E + TB - 1) / TB;
    const int gb_nodes  = (N + 3) / 4;

    // ---- CSR build (shared by all 3 layers) ----
    zero_ints<<<(2 * N + TB - 1) / TB, TB, 0, stream>>>(deg, 2 * N);  // deg+cursor
    hist_deg<<<gb_edges, TB, 0, stream>>>(dst, deg);
    scan_offsets<<<1, 1024, 0, stream>>>(deg, offs, N);
    build_csr<<<gb_edges, TB, 0, stream>>>(src, dst, offs, cursor, csr_src);

    // ---- layer 0: 256 -> 8 heads x 16, ELU ----
    gemm_attn<256, 128, 16><<<gb_rows64, 256, 0, stream>>>(x, W0, al0, ar0, feat, elb, erb, N);
    node_flash_agg<8, 16, true><<<gb_nodes, 256, 0, stream>>>(
        offs, csr_src, elb, erb, feat, b0, hbuf, N);

    // ---- layer 1: 128 -> 8 heads x 16, ELU ----
    gemm_attn<128, 128, 16><<<gb_rows64, 256, 0, stream>>>(hbuf, W1, al1, ar1, feat, elb, erb, N);
    node_flash_agg<8, 16, true><<<gb_nodes, 256, 0, stream>>>(
        offs, csr_src, elb, erb, feat, b1, hbuf, N);

    // ---- layer 2: 128 -> 1 head x 64, no act ----
    gemm_attn<128, 64, 64><<<gb_rows64, 256, 0, stream>>>(hbuf, W2, al2, ar2, feat, elb, erb, N);
    node_flash_agg<1, 64, false><<<gb_nodes, 256, 0, stream>>>(
        offs, csr_src, elb, erb, feat, b2, out, N);
}

// Round 6
// 413.392 us; speedup vs baseline: 1.7838x; 1.7838x over previous
//
#include <hip/hip_runtime.h>
#include <hip/hip_bf16.h>
#include <cstdint>

#define N_NODES 50000
#define N_EDGES 800000

// ---------------------------------------------------------------------------
// feat = X @ W  and el/er = per-head attention dots.
// Block: 256 threads, tile 64 rows x DOUT cols. Thread (tr,tc) = (tid/16,
// tid%16) owns rows tr*4..+3 and cols tc*CN..+CN-1 (CN = DOUT/16).
// Both X and W staged in LDS per 64-wide k-phase; per k-quad: 4 x-b128 +
// CN w-b128 feed 16*CN FMAs -> ~90% FMA issue. Bank-tuned layouts:
//   xs[64][68]           : aligned float4 rows, reads hit 4 distinct quads
//   ws[16][KP*CN+4]      : thread-contiguous, read quad-index == tc (16 distinct)
template<int DIN, int DOUT, int F>
__global__ __launch_bounds__(256) void gemm_attn(
    const float* __restrict__ X, const float* __restrict__ W,
    const float* __restrict__ al, const float* __restrict__ ar,
    float* __restrict__ feat, float* __restrict__ el, float* __restrict__ er, int N)
{
    constexpr int KP   = 64;            // k-phase size
    constexpr int NPH  = DIN / KP;      // phases
    constexpr int CN   = DOUT / 16;     // cols per thread (8 or 4)
    constexpr int H    = DOUT / F;
    constexpr int XSTR = KP + 4;        // 68 floats: 16B-aligned rows
    constexpr int WSTR = KP * CN + 4;   // padded w-group stride

    __shared__ float xs[64][XSTR];
    __shared__ float ws[16][WSTR];

    const int tid  = threadIdx.x;
    const int tr   = tid >> 4;          // 0..15 row group
    const int tc   = tid & 15;          // 0..15 col group
    const int row0 = blockIdx.x * 64;

    float acc[4][CN];
#pragma unroll
    for (int r = 0; r < 4; ++r)
#pragma unroll
        for (int c = 0; c < CN; ++c) acc[r][c] = 0.f;

    for (int ph = 0; ph < NPH; ++ph) {
        __syncthreads();
        // stage X: 64 rows x KP cols (float4 coalesced)
#pragma unroll
        for (int i = 0; i < 64 * (KP / 4) / 256; ++i) {
            int s = tid + i * 256;
            int r = s >> 4, q = s & 15;
            int rr = min(row0 + r, N - 1);
            const float4 v = *reinterpret_cast<const float4*>(
                &X[(size_t)rr * DIN + ph * KP + 4 * q]);
            *reinterpret_cast<float4*>(&xs[r][4 * q]) = v;
        }
        // stage W: KP rows x DOUT cols -> ws[group][k*CN + off]
#pragma unroll
        for (int i = 0; i < KP * (DOUT / 4) / 256; ++i) {
            int s = tid + i * 256;
            int k = s / (DOUT / 4), c4 = (s % (DOUT / 4)) * 4;
            const float4 v = *reinterpret_cast<const float4*>(
                &W[(size_t)(ph * KP + k) * DOUT + c4]);
            *reinterpret_cast<float4*>(&ws[c4 / CN][k * CN + (c4 % CN)]) = v;
        }
        __syncthreads();

#pragma unroll 2
        for (int k4 = 0; k4 < KP / 4; ++k4) {
            float4 xv[4];
#pragma unroll
            for (int rr = 0; rr < 4; ++rr)
                xv[rr] = *reinterpret_cast<const float4*>(&xs[tr * 4 + rr][k4 * 4]);
            float wv[4][CN];
#pragma unroll
            for (int kk = 0; kk < 4; ++kk)
#pragma unroll
                for (int j = 0; j < CN / 4; ++j)
                    *reinterpret_cast<float4*>(&wv[kk][4 * j]) =
                        *reinterpret_cast<const float4*>(&ws[tc][(k4 * 4 + kk) * CN + 4 * j]);
#pragma unroll
            for (int kk = 0; kk < 4; ++kk)
#pragma unroll
                for (int rr = 0; rr < 4; ++rr) {
                    const float xk = (kk == 0) ? xv[rr].x : (kk == 1) ? xv[rr].y
                                   : (kk == 2) ? xv[rr].z : xv[rr].w;
#pragma unroll
                    for (int c = 0; c < CN; ++c)
                        acc[rr][c] = fmaf(xk, wv[kk][c], acc[rr][c]);
                }
        }
    }

    // ---- attention dots: thread-local partial + shfl reduce over F/CN lanes ----
    constexpr int RW = F / CN;          // reduce width (2 for L0/L1, 16 for L2)
    float alv[CN], arv[CN];
#pragma unroll
    for (int c = 0; c < CN; ++c) { alv[c] = al[tc * CN + c]; arv[c] = ar[tc * CN + c]; }

#pragma unroll
    for (int rr = 0; rr < 4; ++rr) {
        int row = row0 + tr * 4 + rr;
        float pl = 0.f, pr = 0.f;
#pragma unroll
        for (int c = 0; c < CN; ++c) {
            pl = fmaf(acc[rr][c], alv[c], pl);
            pr = fmaf(acc[rr][c], arv[c], pr);
        }
#pragma unroll
        for (int off = 1; off < RW; off <<= 1) {
            pl += __shfl_xor(pl, off);
            pr += __shfl_xor(pr, off);
        }
        if (row < N && (tc % RW) == 0) {
            int h = (tc * CN) / F;
            el[(size_t)row * H + h] = pl;
            er[(size_t)row * H + h] = pr;
        }
    }

    // ---- feat store (contiguous CN cols per thread) ----
#pragma unroll
    for (int rr = 0; rr < 4; ++rr) {
        int row = row0 + tr * 4 + rr;
        if (row < N) {
#pragma unroll
            for (int j = 0; j < CN / 4; ++j) {
                float4 v = make_float4(acc[rr][4 * j], acc[rr][4 * j + 1],
                                       acc[rr][4 * j + 2], acc[rr][4 * j + 3]);
                *reinterpret_cast<float4*>(&feat[(size_t)row * DOUT + tc * CN + 4 * j]) = v;
            }
        }
    }
}

// ---------------------------------------------------------------------------
// CSR build (dst-sorted), shared by all 3 layers
__global__ void zero_ints(int* __restrict__ a, int n)
{
    int i = blockIdx.x * blockDim.x + threadIdx.x;
    if (i < n) a[i] = 0;
}

__global__ void hist_deg(const int* __restrict__ dst, int* __restrict__ deg)
{
    int e = blockIdx.x * blockDim.x + threadIdx.x;
    if (e < N_EDGES) atomicAdd(&deg[dst[e]], 1);
}

// single block, 1024 threads: exclusive scan of deg[0..n) -> offs[0..n]
__global__ __launch_bounds__(1024) void scan_offsets(
    const int* __restrict__ deg, int* __restrict__ offs, int n)
{
    __shared__ int wtot[16], wincl[16];
    __shared__ int carry_s;
    const int tid = threadIdx.x;
    const int lane = tid & 63, wid = tid >> 6;
    if (tid == 0) carry_s = 0;
    __syncthreads();
    for (int base = 0; base < n; base += 1024) {
        int i = base + tid;
        int v = (i < n) ? deg[i] : 0;
        int x = v;
#pragma unroll
        for (int off = 1; off < 64; off <<= 1) {
            int t = __shfl_up(x, off);
            if (lane >= off) x += t;
        }
        if (lane == 63) wtot[wid] = x;
        __syncthreads();
        if (tid < 16) {
            int wx = wtot[tid];
#pragma unroll
            for (int off = 1; off < 16; off <<= 1) {
                int t = __shfl_up(wx, off);
                if (tid >= off) wx += t;
            }
            wincl[tid] = wx;
        }
        __syncthreads();
        int waveExcl = (wid == 0) ? 0 : wincl[wid - 1];
        if (i < n) offs[i] = carry_s + waveExcl + (x - v);
        int total = wincl[15];
        __syncthreads();
        if (tid == 0) carry_s += total;
        __syncthreads();
    }
    if (threadIdx.x == 0) offs[n] = carry_s;
}

__global__ void build_csr(const int* __restrict__ src, const int* __restrict__ dst,
                          const int* __restrict__ offs, int* __restrict__ cursor,
                          int* __restrict__ csr_src)
{
    int e = blockIdx.x * blockDim.x + threadIdx.x;
    if (e >= N_EDGES) return;
    int d = dst[e];
    int p = offs[d] + atomicAdd(&cursor[d], 1);
    csr_src[p] = src[e];
}

// ---------------------------------------------------------------------------
// Fused flash-style softmax + aggregation per dst node. One wave per node.
template<int H, int F, bool ACT>
__global__ __launch_bounds__(256) void node_flash_agg(
    const int* __restrict__ offs, const int* __restrict__ csr_src,
    const float* __restrict__ el, const float* __restrict__ er,
    const float* __restrict__ feat, const float* __restrict__ bias,
    float* __restrict__ out, int N)
{
    constexpr int D = H * F;
    constexpr int CPT = D / 64;     // components per lane (2 or 1)
    constexpr int EPC = 64 / H;     // edges per chunk (8 or 64)
    constexpr int SB = 8;           // feat-load batch depth

    const int wid = threadIdx.x >> 6;
    const int lane = threadIdx.x & 63;
    const int n = blockIdx.x * 4 + wid;
    if (n >= N) return;

    const int beg = offs[n];
    const int deg = offs[n + 1] - beg;

    const int h = lane % H;
    const int esub = lane / H;
    const float erd = er[(size_t)n * H + h];

    float m_run = -1e30f, s_run = 0.f;
    float acc[CPT];
#pragma unroll
    for (int c = 0; c < CPT; ++c) acc[c] = 0.f;

    for (int base = 0; base < deg; base += EPC) {
        int ei = base + esub;
        int s_mine = csr_src[beg + min(ei, deg - 1)];   // clamped for padding
        float v = el[(size_t)s_mine * H + h] + erd;
        v = (v > 0.f) ? v : 0.2f * v;                   // leaky_relu 0.2
        float logit = (ei < deg) ? v : -1e30f;

        float cmax = logit;
#pragma unroll
        for (int off = H; off < 64; off <<= 1)
            cmax = fmaxf(cmax, __shfl_xor(cmax, off));
        float nm = fmaxf(m_run, cmax);
        float scale = __expf(m_run - nm);               // 0 on first chunk
        float ex = __expf(logit - nm);                  // 0 for padded lanes
        float csum = ex;
#pragma unroll
        for (int off = H; off < 64; off <<= 1)
            csum += __shfl_xor(csum, off);
        s_run = s_run * scale + csum;
        m_run = nm;

#pragma unroll
        for (int c = 0; c < CPT; ++c)
            acc[c] *= __shfl(scale, (lane + c * 64) / F);

        int active = min(EPC, deg - base);
        for (int g = 0; g < active; g += SB) {
            float fv[SB][CPT];
#pragma unroll
            for (int ii = 0; ii < SB; ++ii) {
                int sl = __shfl(s_mine, (g + ii) * H);  // edge g+ii src row
#pragma unroll
                for (int c = 0; c < CPT; ++c)
                    fv[ii][c] = feat[(size_t)sl * D + lane + c * 64];
            }
#pragma unroll
            for (int ii = 0; ii < SB; ++ii)
#pragma unroll
                for (int c = 0; c < CPT; ++c) {
                    float exb = __shfl(ex, (g + ii) * H + (lane + c * 64) / F);
                    acc[c] = fmaf(fv[ii][c], exb, acc[c]);
                }
        }
    }

    const float inv = (s_run > 0.f) ? 1.f / s_run : 0.f;
#pragma unroll
    for (int c = 0; c < CPT; ++c) {
        int comp = lane + c * 64;
        float v = acc[c] * __shfl(inv, comp / F) + bias[comp];
        if (ACT) v = (v > 0.f) ? v : expm1f(v);         // ELU alpha=1
        out[(size_t)n * D + comp] = v;
    }
}

// ---------------------------------------------------------------------------
extern "C" void kernel_launch(void* const* d_in, const int* in_sizes, int n_in,
                              void* d_out, int out_size, void* d_ws, size_t ws_size,
                              hipStream_t stream)
{
    const float* x   = (const float*)d_in[0];
    const int*   src = (const int*)d_in[1];
    const int*   dst = (const int*)d_in[2];
    const float* W0  = (const float*)d_in[3];
    const float* al0 = (const float*)d_in[4];
    const float* ar0 = (const float*)d_in[5];
    const float* b0  = (const float*)d_in[6];
    const float* W1  = (const float*)d_in[7];
    const float* al1 = (const float*)d_in[8];
    const float* ar1 = (const float*)d_in[9];
    const float* b1  = (const float*)d_in[10];
    const float* W2  = (const float*)d_in[11];
    const float* al2 = (const float*)d_in[12];
    const float* ar2 = (const float*)d_in[13];
    const float* b2  = (const float*)d_in[14];
    float* out = (float*)d_out;

    const int N = N_NODES, E = N_EDGES;

    float* ws   = (float*)d_ws;
    float* feat = ws;                         // N*128
    float* hbuf = feat + (size_t)N * 128;     // N*128
    float* elb  = hbuf + (size_t)N * 128;     // N*8
    float* erb  = elb + (size_t)N * 8;        // N*8
    int* ibase   = (int*)(erb + (size_t)N * 8);
    int* deg     = ibase;                     // N
    int* cursor  = deg + N;                   // N
    int* offs    = cursor + N;                // N+1
    int* csr_src = offs + N + 1;              // E

    const int TB = 256;
    const int gb_rows64 = (N + 63) / 64;
    const int gb_edges  = (E + TB - 1) / TB;
    const int gb_nodes  = (N + 3) / 4;

    // ---- CSR build (shared by all 3 layers) ----
    zero_ints<<<(2 * N + TB - 1) / TB, TB, 0, stream>>>(deg, 2 * N);  // deg+cursor
    hist_deg<<<gb_edges, TB, 0, stream>>>(dst, deg);
    scan_offsets<<<1, 1024, 0, stream>>>(deg, offs, N);
    build_csr<<<gb_edges, TB, 0, stream>>>(src, dst, offs, cursor, csr_src);

    // ---- layer 0: 256 -> 8 heads x 16, ELU ----
    gemm_attn<256, 128, 16><<<gb_rows64, 256, 0, stream>>>(x, W0, al0, ar0, feat, elb, erb, N);
    node_flash_agg<8, 16, true><<<gb_nodes, 256, 0, stream>>>(
        offs, csr_src, elb, erb, feat, b0, hbuf, N);

    // ---- layer 1: 128 -> 8 heads x 16, ELU ----
    gemm_attn<128, 128, 16><<<gb_rows64, 256, 0, stream>>>(hbuf, W1, al1, ar1, feat, elb, erb, N);
    node_flash_agg<8, 16, true><<<gb_nodes, 256, 0, stream>>>(
        offs, csr_src, elb, erb, feat, b1, hbuf, N);

    // ---- layer 2: 128 -> 1 head x 64, no act ----
    gemm_attn<128, 64, 64><<<gb_rows64, 256, 0, stream>>>(hbuf, W2, al2, ar2, feat, elb, erb, N);
    node_flash_agg<1, 64, false><<<gb_nodes, 256, 0, stream>>>(
        offs, csr_src, elb, erb, feat, b2, out, N);
}

// Round 7
// 402.964 us; speedup vs baseline: 1.8300x; 1.0259x over previous
//
#include <hip/hip_runtime.h>
#include <hip/hip_bf16.h>
#include <cstdint>

#define N_NODES 50000
#define N_EDGES 800000

// ---------------------------------------------------------------------------
// feat = X @ W  and el/er = per-head attention dots.
// Block: 256 threads, tile 64 rows x DOUT cols. Thread (tr,tc) = (tid/16,
// tid%16) owns rows tr*4..+3 and cols tc*CN..+CN-1 (CN = DOUT/16).
template<int DIN, int DOUT, int F>
__global__ __launch_bounds__(256) void gemm_attn(
    const float* __restrict__ X, const float* __restrict__ W,
    const float* __restrict__ al, const float* __restrict__ ar,
    float* __restrict__ feat, float* __restrict__ el, float* __restrict__ er, int N)
{
    constexpr int KP   = 64;            // k-phase size
    constexpr int NPH  = DIN / KP;      // phases
    constexpr int CN   = DOUT / 16;     // cols per thread (8 or 4)
    constexpr int H    = DOUT / F;
    constexpr int XSTR = KP + 4;        // 68 floats: 16B-aligned rows
    constexpr int WSTR = KP * CN + 4;   // padded w-group stride

    __shared__ float xs[64][XSTR];
    __shared__ float ws[16][WSTR];

    const int tid  = threadIdx.x;
    const int tr   = tid >> 4;          // 0..15 row group
    const int tc   = tid & 15;          // 0..15 col group
    const int row0 = blockIdx.x * 64;

    float acc[4][CN];
#pragma unroll
    for (int r = 0; r < 4; ++r)
#pragma unroll
        for (int c = 0; c < CN; ++c) acc[r][c] = 0.f;

    for (int ph = 0; ph < NPH; ++ph) {
        __syncthreads();
        // stage X: 64 rows x KP cols (float4 coalesced)
#pragma unroll
        for (int i = 0; i < 64 * (KP / 4) / 256; ++i) {
            int s = tid + i * 256;
            int r = s >> 4, q = s & 15;
            int rr = min(row0 + r, N - 1);
            const float4 v = *reinterpret_cast<const float4*>(
                &X[(size_t)rr * DIN + ph * KP + 4 * q]);
            *reinterpret_cast<float4*>(&xs[r][4 * q]) = v;
        }
        // stage W: KP rows x DOUT cols -> ws[group][k*CN + off]
#pragma unroll
        for (int i = 0; i < KP * (DOUT / 4) / 256; ++i) {
            int s = tid + i * 256;
            int k = s / (DOUT / 4), c4 = (s % (DOUT / 4)) * 4;
            const float4 v = *reinterpret_cast<const float4*>(
                &W[(size_t)(ph * KP + k) * DOUT + c4]);
            *reinterpret_cast<float4*>(&ws[c4 / CN][k * CN + (c4 % CN)]) = v;
        }
        __syncthreads();

#pragma unroll 2
        for (int k4 = 0; k4 < KP / 4; ++k4) {
            float4 xv[4];
#pragma unroll
            for (int rr = 0; rr < 4; ++rr)
                xv[rr] = *reinterpret_cast<const float4*>(&xs[tr * 4 + rr][k4 * 4]);
            float wv[4][CN];
#pragma unroll
            for (int kk = 0; kk < 4; ++kk)
#pragma unroll
                for (int j = 0; j < CN / 4; ++j)
                    *reinterpret_cast<float4*>(&wv[kk][4 * j]) =
                        *reinterpret_cast<const float4*>(&ws[tc][(k4 * 4 + kk) * CN + 4 * j]);
#pragma unroll
            for (int kk = 0; kk < 4; ++kk)
#pragma unroll
                for (int rr = 0; rr < 4; ++rr) {
                    const float xk = (kk == 0) ? xv[rr].x : (kk == 1) ? xv[rr].y
                                   : (kk == 2) ? xv[rr].z : xv[rr].w;
#pragma unroll
                    for (int c = 0; c < CN; ++c)
                        acc[rr][c] = fmaf(xk, wv[kk][c], acc[rr][c]);
                }
        }
    }

    // ---- attention dots: thread-local partial + shfl reduce over F/CN lanes ----
    constexpr int RW = F / CN;          // reduce width (2 for L0/L1, 16 for L2)
    float alv[CN], arv[CN];
#pragma unroll
    for (int c = 0; c < CN; ++c) { alv[c] = al[tc * CN + c]; arv[c] = ar[tc * CN + c]; }

#pragma unroll
    for (int rr = 0; rr < 4; ++rr) {
        int row = row0 + tr * 4 + rr;
        float pl = 0.f, pr = 0.f;
#pragma unroll
        for (int c = 0; c < CN; ++c) {
            pl = fmaf(acc[rr][c], alv[c], pl);
            pr = fmaf(acc[rr][c], arv[c], pr);
        }
#pragma unroll
        for (int off = 1; off < RW; off <<= 1) {
            pl += __shfl_xor(pl, off);
            pr += __shfl_xor(pr, off);
        }
        if (row < N && (tc % RW) == 0) {
            int h = (tc * CN) / F;
            el[(size_t)row * H + h] = pl;
            er[(size_t)row * H + h] = pr;
        }
    }

    // ---- feat store (contiguous CN cols per thread) ----
#pragma unroll
    for (int rr = 0; rr < 4; ++rr) {
        int row = row0 + tr * 4 + rr;
        if (row < N) {
#pragma unroll
            for (int j = 0; j < CN / 4; ++j) {
                float4 v = make_float4(acc[rr][4 * j], acc[rr][4 * j + 1],
                                       acc[rr][4 * j + 2], acc[rr][4 * j + 3]);
                *reinterpret_cast<float4*>(&feat[(size_t)row * DOUT + tc * CN + 4 * j]) = v;
            }
        }
    }
}

// ---------------------------------------------------------------------------
// CSR build (dst-sorted), shared by all 3 layers
__global__ void zero_ints(int* __restrict__ a, int n)
{
    int i = blockIdx.x * blockDim.x + threadIdx.x;
    if (i < n) a[i] = 0;
}

__global__ void hist_deg(const int* __restrict__ dst, int* __restrict__ deg)
{
    int e = blockIdx.x * blockDim.x + threadIdx.x;
    if (e < N_EDGES) atomicAdd(&deg[dst[e]], 1);
}

// single block, 1024 threads: exclusive scan of deg[0..n) -> offs[0..n]
__global__ __launch_bounds__(1024) void scan_offsets(
    const int* __restrict__ deg, int* __restrict__ offs, int n)
{
    __shared__ int wtot[16], wincl[16];
    __shared__ int carry_s;
    const int tid = threadIdx.x;
    const int lane = tid & 63, wid = tid >> 6;
    if (tid == 0) carry_s = 0;
    __syncthreads();
    for (int base = 0; base < n; base += 1024) {
        int i = base + tid;
        int v = (i < n) ? deg[i] : 0;
        int x = v;
#pragma unroll
        for (int off = 1; off < 64; off <<= 1) {
            int t = __shfl_up(x, off);
            if (lane >= off) x += t;
        }
        if (lane == 63) wtot[wid] = x;
        __syncthreads();
        if (tid < 16) {
            int wx = wtot[tid];
#pragma unroll
            for (int off = 1; off < 16; off <<= 1) {
                int t = __shfl_up(wx, off);
                if (tid >= off) wx += t;
            }
            wincl[tid] = wx;
        }
        __syncthreads();
        int waveExcl = (wid == 0) ? 0 : wincl[wid - 1];
        if (i < n) offs[i] = carry_s + waveExcl + (x - v);
        int total = wincl[15];
        __syncthreads();
        if (tid == 0) carry_s += total;
        __syncthreads();
    }
    if (threadIdx.x == 0) offs[n] = carry_s;
}

__global__ void build_csr(const int* __restrict__ src, const int* __restrict__ dst,
                          const int* __restrict__ offs, int* __restrict__ cursor,
                          int* __restrict__ csr_src)
{
    int e = blockIdx.x * blockDim.x + threadIdx.x;
    if (e >= N_EDGES) return;
    int d = dst[e];
    int p = offs[d] + atomicAdd(&cursor[d], 1);
    csr_src[p] = src[e];
}

// ---------------------------------------------------------------------------
// Fused flash-style softmax + aggregation per dst node. One wave per node.
// comp mapping: comp = CPT*lane + c  -> one float2 VMEM instr per row gather.
// Next-chunk csr/el prefetch hides the logit gather latency under weighting.
template<int H, int F, bool ACT>
__global__ __launch_bounds__(256) void node_flash_agg(
    const int* __restrict__ offs, const int* __restrict__ csr_src,
    const float* __restrict__ el, const float* __restrict__ er,
    const float* __restrict__ feat, const float* __restrict__ bias,
    float* __restrict__ out, int N)
{
    constexpr int D = H * F;
    constexpr int CPT = D / 64;     // components per lane (2 or 1)
    constexpr int EPC = 64 / H;     // edges per chunk (8 or 64)
    constexpr int SB = 8;           // feat-load batch depth

    const int wid = threadIdx.x >> 6;
    const int lane = threadIdx.x & 63;
    const int n = blockIdx.x * 4 + wid;
    if (n >= N) return;

    const int beg = offs[n];
    const int deg = offs[n + 1] - beg;

    const int comp0 = CPT * lane;           // my first component
    const int myhead = comp0 / F;           // both comps in same head (CPT<=2, F>=16)

    if (deg == 0) {                         // empty segment: out = act(bias)
#pragma unroll
        for (int c = 0; c < CPT; ++c) {
            float v = bias[comp0 + c];
            if (ACT) v = (v > 0.f) ? v : expm1f(v);
            out[(size_t)n * D + comp0 + c] = v;
        }
        return;
    }

    const int h = lane % H;
    const int esub = lane / H;
    const float erd = er[(size_t)n * H + h];

    float m_run = -1e30f, s_run = 0.f;
    float acc[CPT];
#pragma unroll
    for (int c = 0; c < CPT; ++c) acc[c] = 0.f;

    // prefetch chunk 0 logits inputs
    int sN = csr_src[beg + min(esub, deg - 1)];
    float elN = el[(size_t)sN * H + h];

    for (int base = 0; base < deg; base += EPC) {
        const int s_mine = sN;
        const float elv = elN;
        const int nb = base + EPC;
        if (nb < deg) {                     // issue next chunk's loads early
            sN = csr_src[beg + min(nb + esub, deg - 1)];
            elN = el[(size_t)sN * H + h];
        }

        float v = elv + erd;
        v = (v > 0.f) ? v : 0.2f * v;       // leaky_relu 0.2
        float logit = (base + esub < deg) ? v : -1e30f;

        float cmax = logit;
#pragma unroll
        for (int off = H; off < 64; off <<= 1)
            cmax = fmaxf(cmax, __shfl_xor(cmax, off));
        float nm = fmaxf(m_run, cmax);
        float scale = __expf(m_run - nm);
        float ex = __expf(logit - nm);      // 0 for padded lanes
        float csum = ex;
#pragma unroll
        for (int off = H; off < 64; off <<= 1)
            csum += __shfl_xor(csum, off);
        s_run = s_run * scale + csum;
        m_run = nm;

        const float sc = __shfl(scale, myhead);
#pragma unroll
        for (int c = 0; c < CPT; ++c) acc[c] *= sc;

        const int active = min(EPC, deg - base);
        for (int g = 0; g < active; g += SB) {
            float fv[SB][CPT];
#pragma unroll
            for (int ii = 0; ii < SB; ++ii) {
                int sl = __shfl(s_mine, (g + ii) * H);  // edge's src row
                if constexpr (CPT == 2) {
                    float2 t = *reinterpret_cast<const float2*>(
                        &feat[(size_t)sl * D + comp0]);
                    fv[ii][0] = t.x; fv[ii][1] = t.y;
                } else {
                    fv[ii][0] = feat[(size_t)sl * D + comp0];
                }
            }
#pragma unroll
            for (int ii = 0; ii < SB; ++ii) {
                float exb = __shfl(ex, (g + ii) * H + myhead);
#pragma unroll
                for (int c = 0; c < CPT; ++c)
                    acc[c] = fmaf(fv[ii][c], exb, acc[c]);
            }
        }
    }

    const float inv = 1.f / s_run;
    const float invb = __shfl(inv, myhead);
#pragma unroll
    for (int c = 0; c < CPT; ++c) {
        float v = acc[c] * invb + bias[comp0 + c];
        if (ACT) v = (v > 0.f) ? v : expm1f(v);         // ELU alpha=1
        acc[c] = v;
    }
    if constexpr (CPT == 2) {
        *reinterpret_cast<float2*>(&out[(size_t)n * D + comp0]) =
            make_float2(acc[0], acc[1]);
    } else {
        out[(size_t)n * D + comp0] = acc[0];
    }
}

// ---------------------------------------------------------------------------
extern "C" void kernel_launch(void* const* d_in, const int* in_sizes, int n_in,
                              void* d_out, int out_size, void* d_ws, size_t ws_size,
                              hipStream_t stream)
{
    const float* x   = (const float*)d_in[0];
    const int*   src = (const int*)d_in[1];
    const int*   dst = (const int*)d_in[2];
    const float* W0  = (const float*)d_in[3];
    const float* al0 = (const float*)d_in[4];
    const float* ar0 = (const float*)d_in[5];
    const float* b0  = (const float*)d_in[6];
    const float* W1  = (const float*)d_in[7];
    const float* al1 = (const float*)d_in[8];
    const float* ar1 = (const float*)d_in[9];
    const float* b1  = (const float*)d_in[10];
    const float* W2  = (const float*)d_in[11];
    const float* al2 = (const float*)d_in[12];
    const float* ar2 = (const float*)d_in[13];
    const float* b2  = (const float*)d_in[14];
    float* out = (float*)d_out;

    const int N = N_NODES, E = N_EDGES;

    float* ws   = (float*)d_ws;
    float* feat = ws;                         // N*128
    float* hbuf = feat + (size_t)N * 128;     // N*128
    float* elb  = hbuf + (size_t)N * 128;     // N*8
    float* erb  = elb + (size_t)N * 8;        // N*8
    int* ibase   = (int*)(erb + (size_t)N * 8);
    int* deg     = ibase;                     // N
    int* cursor  = deg + N;                   // N
    int* offs    = cursor + N;                // N+1
    int* csr_src = offs + N + 1;              // E

    const int TB = 256;
    const int gb_rows64 = (N + 63) / 64;
    const int gb_edges  = (E + TB - 1) / TB;
    const int gb_nodes  = (N + 3) / 4;

    // ---- CSR build (shared by all 3 layers) ----
    zero_ints<<<(2 * N + TB - 1) / TB, TB, 0, stream>>>(deg, 2 * N);  // deg+cursor
    hist_deg<<<gb_edges, TB, 0, stream>>>(dst, deg);
    scan_offsets<<<1, 1024, 0, stream>>>(deg, offs, N);
    build_csr<<<gb_edges, TB, 0, stream>>>(src, dst, offs, cursor, csr_src);

    // ---- layer 0: 256 -> 8 heads x 16, ELU ----
    gemm_attn<256, 128, 16><<<gb_rows64, 256, 0, stream>>>(x, W0, al0, ar0, feat, elb, erb, N);
    node_flash_agg<8, 16, true><<<gb_nodes, 256, 0, stream>>>(
        offs, csr_src, elb, erb, feat, b0, hbuf, N);

    // ---- layer 1: 128 -> 8 heads x 16, ELU ----
    gemm_attn<128, 128, 16><<<gb_rows64, 256, 0, stream>>>(hbuf, W1, al1, ar1, feat, elb, erb, N);
    node_flash_agg<8, 16, true><<<gb_nodes, 256, 0, stream>>>(
        offs, csr_src, elb, erb, feat, b1, hbuf, N);

    // ---- layer 2: 128 -> 1 head x 64, no act ----
    gemm_attn<128, 64, 64><<<gb_rows64, 256, 0, stream>>>(hbuf, W2, al2, ar2, feat, elb, erb, N);
    node_flash_agg<1, 64, false><<<gb_nodes, 256, 0, stream>>>(
        offs, csr_src, elb, erb, feat, b2, out, N);
}